// Round 4
// baseline (861.078 us; speedup 1.0000x reference)
//
#include <hip/hip_runtime.h>

typedef short bf16x8 __attribute__((ext_vector_type(8)));
typedef float f32x4 __attribute__((ext_vector_type(4)));

#define K_CODES 1024
#define D_DIM   256
#define HWSZ    1024
#define OUT_ELEMS 16777216

__device__ __forceinline__ unsigned short f2bf(float x) {
    unsigned int u = __float_as_uint(x);
    u += 0x7FFFu + ((u >> 16) & 1u);   // RNE
    return (unsigned short)(u >> 16);
}

__device__ __forceinline__ unsigned long long pack4bf(float a, float b, float c, float d) {
    unsigned long long u0 = f2bf(a), u1 = f2bf(b), u2 = f2bf(c), u3 = f2bf(d);
    return u0 | (u1 << 16) | (u2 << 32) | (u3 << 48);
}

// -------- prep: ||e_k||^2 per code + zero the loss accumulator --------
__global__ void enorm_kernel(const float* __restrict__ emb,
                             float* __restrict__ eNorm,
                             float* __restrict__ lossAcc) {
    int k = blockIdx.x;          // 1024 blocks
    int lane = threadIdx.x;      // 64 threads
    const float4* row = reinterpret_cast<const float4*>(emb + k * D_DIM);
    float4 v = row[lane];
    float s = v.x * v.x + v.y * v.y + v.z * v.z + v.w * v.w;
    #pragma unroll
    for (int off = 32; off > 0; off >>= 1) s += __shfl_down(s, off, 64);
    if (lane == 0) eNorm[k] = s;
    if (k == 0 && lane == 0) *lossAcc = 0.0f;
}

// -------- prep: pack E into B-fragment order with permuted k-mapping --------
// lane l elem e  <-  E[ctile*16 + (l&15)][dc*32 + (e>>2)*16 + (l>>4)*4 + (e&3)]
__global__ void pack_e(const float* __restrict__ emb, bf16x8* __restrict__ Ep) {
    int fid = blockIdx.x;        // 512 = ctile*8 + dc
    int l = threadIdx.x;         // 64
    int ctile = fid >> 3, dc = fid & 7;
    const float* src = emb + (ctile * 16 + (l & 15)) * D_DIM + dc * 32 + ((l >> 4) << 2);
    float4 f0 = *reinterpret_cast<const float4*>(src);        // e = 0..3
    float4 f1 = *reinterpret_cast<const float4*>(src + 16);   // e = 4..7
    bf16x8 v;
    v[0] = (short)f2bf(f0.x); v[1] = (short)f2bf(f0.y);
    v[2] = (short)f2bf(f0.z); v[3] = (short)f2bf(f0.w);
    v[4] = (short)f2bf(f1.x); v[5] = (short)f2bf(f1.y);
    v[6] = (short)f2bf(f1.z); v[7] = (short)f2bf(f1.w);
    Ep[fid * 64 + l] = v;
}

// -------- fused main: 64-row blocks, 4 blocks/CU --------
// 1024 blocks x 256 thr (4 waves). Wave w owns cols [w*256, w*256+256), all 64 rows.
__launch_bounds__(256, 4)
__global__ void vq_main(const float* __restrict__ lat, const bf16x8* __restrict__ Ep,
                        const float* __restrict__ eNorm, const float* __restrict__ emb,
                        float* __restrict__ out, float* __restrict__ lossAcc) {
    __shared__ char smem[33024];                 // Xs64 (32 KB) / Qs (33 KB) overlay
    unsigned long long* Xs64 = reinterpret_cast<unsigned long long*>(smem); // [q 0..63][r 0..63]
    float* Qs = reinterpret_cast<float*>(smem);  // [r 0..63][129]
    __shared__ float xsqW[4];
    __shared__ float wbV[256];                   // [row][w]
    __shared__ int   wbI[256];
    __shared__ int   idxs[64];

    const int t = threadIdx.x;
    const int lane = t & 63;
    const int w = t >> 6;
    const int l15 = lane & 15, lhi = lane >> 4;
    const int R0 = blockIdx.x * 64;
    const float* latB = lat + (R0 >> 10) * (D_DIM * HWSZ) + (R0 & 1023);

    // ---- stage X tile: global (d-major) -> bf16 LDS [q][r], accumulate ||x||^2 ----
    float xsq = 0.0f;
    {
        const int r = lane;
        const int qBase = w * 16;
        #pragma unroll 4
        for (int qi = 0; qi < 16; ++qi) {
            const int q = qBase + qi;
            const float* src = latB + (q * 4) * HWSZ + r;
            float v0 = src[0];
            float v1 = src[HWSZ];
            float v2 = src[2 * HWSZ];
            float v3 = src[3 * HWSZ];
            xsq += v0 * v0 + v1 * v1 + v2 * v2 + v3 * v3;
            Xs64[q * 64 + r] = pack4bf(v0, v1, v2, v3);
        }
    }
    #pragma unroll
    for (int off = 32; off > 0; off >>= 1) xsq += __shfl_down(xsq, off, 64);
    if (lane == 0) xsqW[w] = xsq;
    __syncthreads();

    // ---- MFMA distance + running argmin (cols w*256 + ct*64 + j*16 + l15) ----
    float best[4][4];
    int   bidx[4][4];
    #pragma unroll
    for (int i = 0; i < 4; ++i)
        #pragma unroll
        for (int rs = 0; rs < 4; ++rs) { best[i][rs] = 3.4e38f; bidx[i][rs] = 0; }

    #pragma unroll
    for (int ct = 0; ct < 4; ++ct) {
        f32x4 acc[4][4];
        #pragma unroll
        for (int j = 0; j < 4; ++j) {
            // fold ||e||^2 into accumulator init: C = -en/2, score = -2*accFinal
            const float c0 = -0.5f * eNorm[w * 256 + ct * 64 + j * 16 + l15];
            #pragma unroll
            for (int i = 0; i < 4; ++i) acc[i][j] = (f32x4){c0, c0, c0, c0};
        }

        #pragma unroll
        for (int dc = 0; dc < 8; ++dc) {
            bf16x8 bfr[4], afr[4];
            #pragma unroll
            for (int j = 0; j < 4; ++j)
                bfr[j] = Ep[((w * 16 + ct * 4 + j) * 8 + dc) * 64 + lane];
            #pragma unroll
            for (int i = 0; i < 4; ++i) {
                const int r = i * 16 + l15;
                union { unsigned long long u[2]; bf16x8 v; } fr;
                fr.u[0] = Xs64[(dc * 8 + lhi) * 64 + r];
                fr.u[1] = Xs64[(dc * 8 + 4 + lhi) * 64 + r];
                afr[i] = fr.v;
            }
            #pragma unroll
            for (int i = 0; i < 4; ++i)
                #pragma unroll
                for (int j = 0; j < 4; ++j)
                    acc[i][j] = __builtin_amdgcn_mfma_f32_16x16x32_bf16(afr[i], bfr[j], acc[i][j], 0, 0, 0);
        }
        #pragma unroll
        for (int j = 0; j < 4; ++j) {
            const int k = w * 256 + ct * 64 + j * 16 + l15;
            #pragma unroll
            for (int i = 0; i < 4; ++i)
                #pragma unroll
                for (int rs = 0; rs < 4; ++rs) {
                    float s = -2.0f * acc[i][j][rs];
                    if (s < best[i][rs]) { best[i][rs] = s; bidx[i][rs] = k; }
                }
        }
    }

    // ---- argmin reduce over l15 lanes, dump per-wave candidate ----
    #pragma unroll
    for (int i = 0; i < 4; ++i)
        #pragma unroll
        for (int rs = 0; rs < 4; ++rs) {
            float v = best[i][rs]; int ix = bidx[i][rs];
            #pragma unroll
            for (int m = 1; m <= 8; m <<= 1) {
                float ov = __shfl_xor(v, m, 64);
                int   oi = __shfl_xor(ix, m, 64);
                if (ov < v || (ov == v && oi < ix)) { v = ov; ix = oi; }
            }
            if (l15 == 0) {
                const int row = i * 16 + lhi * 4 + rs;
                wbV[row * 4 + w] = v;
                wbI[row * 4 + w] = ix;
            }
        }
    __syncthreads();

    if (t < 64) {
        float bv = wbV[t * 4]; int bi = wbI[t * 4];
        #pragma unroll
        for (int c = 1; c < 4; ++c) {
            float v = wbV[t * 4 + c]; int ii = wbI[t * 4 + c];
            if (v < bv || (v == bv && ii < bi)) { bv = v; bi = ii; }
        }
        idxs[t] = bi;
        float lsum = bv;   // = eNorm[bi] - 2*dot
        #pragma unroll
        for (int off = 32; off > 0; off >>= 1) lsum += __shfl_down(lsum, off, 64);
        if (t == 0)
            atomicAdd(lossAcc, lsum + xsqW[0] + xsqW[1] + xsqW[2] + xsqW[3]);
    }
    __syncthreads();   // idxs visible; Xs64 dead -> reuse as Qs

    // ---- epilogue: gather emb -> LDS -> full-line coalesced out writes ----
    float* outB = out + (R0 >> 10) * (D_DIM * HWSZ) + (R0 & 1023);
    #pragma unroll
    for (int p = 0; p < 2; ++p) {   // d-halves: full 256B line per (d) written once
        #pragma unroll
        for (int s = 0; s < 8; ++s) {
            const int slot = s * 256 + t;       // 0..2047
            const int rloc = slot >> 5;         // 0..63
            const int ch = slot & 31;           // float4 chunk in 128 d
            const float4 qv = *reinterpret_cast<const float4*>(
                emb + idxs[rloc] * D_DIM + p * 128 + ch * 4);
            float* dst = &Qs[rloc * 129 + ch * 4];
            dst[0] = qv.x; dst[1] = qv.y; dst[2] = qv.z; dst[3] = qv.w;
        }
        __syncthreads();
        #pragma unroll
        for (int it = 0; it < 32; ++it) {
            const int dp = it * 4 + w;          // 0..127
            outB[(p * 128 + dp) * HWSZ + lane] = Qs[lane * 129 + dp];
        }
        __syncthreads();
    }
}

// -------- finalize: write the two loss scalars --------
__global__ void finalize_kernel(const float* __restrict__ lossAcc,
                                float* __restrict__ out_tail) {
    float mse = *lossAcc * (1.0f / 16777216.0f);
    out_tail[0] = mse;          // embedding_loss
    out_tail[1] = 0.25f * mse;  // BETA * commitment_loss
}

extern "C" void kernel_launch(void* const* d_in, const int* in_sizes, int n_in,
                              void* d_out, int out_size, void* d_ws, size_t ws_size,
                              hipStream_t stream) {
    (void)in_sizes; (void)n_in; (void)out_size; (void)ws_size;
    const float* lat = (const float*)d_in[0];
    const float* emb = (const float*)d_in[1];
    float* out = (float*)d_out;

    char* ws = (char*)d_ws;
    bf16x8* Ep      = (bf16x8*)ws;                       // 512 KB
    float*  eNorm   = (float*)(ws + (512u << 10));       // 4 KB
    float*  lossAcc = eNorm + K_CODES;                   // 4 B

    hipLaunchKernelGGL(enorm_kernel, dim3(K_CODES), dim3(64), 0, stream,
                       emb, eNorm, lossAcc);
    hipLaunchKernelGGL(pack_e, dim3(512), dim3(64), 0, stream, emb, Ep);
    hipLaunchKernelGGL(vq_main, dim3(1024), dim3(256), 0, stream,
                       lat, Ep, eNorm, emb, out, lossAcc);
    hipLaunchKernelGGL(finalize_kernel, dim3(1), dim3(1), 0, stream,
                       lossAcc, out + OUT_ELEMS);
}

// Round 5
// 312.167 us; speedup vs baseline: 2.7584x; 2.7584x over previous
//
#include <hip/hip_runtime.h>

typedef short bf16x8 __attribute__((ext_vector_type(8)));
typedef float f32x4 __attribute__((ext_vector_type(4)));

#define K_CODES 1024
#define D_DIM   256
#define HWSZ    1024
#define OUT_ELEMS 16777216

__device__ __forceinline__ unsigned short f2bf(float x) {
    unsigned int u = __float_as_uint(x);
    u += 0x7FFFu + ((u >> 16) & 1u);   // RNE
    return (unsigned short)(u >> 16);
}

__device__ __forceinline__ unsigned long long pack4bf(float a, float b, float c, float d) {
    unsigned long long u0 = f2bf(a), u1 = f2bf(b), u2 = f2bf(c), u3 = f2bf(d);
    return u0 | (u1 << 16) | (u2 << 32) | (u3 << 48);
}

// order-preserving float -> uint key (increasing)
__device__ __forceinline__ unsigned int fkey(float s) {
    unsigned int u = __float_as_uint(s);
    return (u & 0x80000000u) ? ~u : (u | 0x80000000u);
}
__device__ __forceinline__ float fkey_inv(unsigned int k) {
    unsigned int u = (k & 0x80000000u) ? (k & 0x7FFFFFFFu) : ~k;
    return __uint_as_float(u);
}

// -------- prep: pack E into B-frag order + ||e||^2 + zero loss --------
// 64 blocks x 256 thr; block = ctile (16 codes x 256 d)
__global__ void pack_e2(const float* __restrict__ emb, unsigned long long* __restrict__ Ep64,
                        float* __restrict__ eNorm, float* __restrict__ lossAcc) {
    const int ctile = blockIdx.x;
    const int t = threadIdx.x;
    const int lane = t & 63;
    #pragma unroll
    for (int p = 0; p < 4; ++p) {
        const int code_loc = p * 4 + (t >> 6);          // 0..15
        const int code = ctile * 16 + code_loc;
        const float4 v = *reinterpret_cast<const float4*>(emb + code * D_DIM + lane * 4);
        float s = v.x * v.x + v.y * v.y + v.z * v.z + v.w * v.w;
        #pragma unroll
        for (int off = 32; off > 0; off >>= 1) s += __shfl_down(s, off, 64);
        if (lane == 0) eNorm[code] = s;
        // frag slot for d0 = lane*4
        const int dc  = lane >> 3;
        const int lhi = lane & 3;
        const int ehi = (lane >> 2) & 1;
        Ep64[(((ctile * 8 + dc) * 64) + lhi * 16 + code_loc) * 2 + ehi] =
            pack4bf(v.x, v.y, v.z, v.w);
    }
    if (ctile == 0 && t == 0) *lossAcc = 0.0f;
}

// -------- fused main: 64-row blocks --------
// 1024 blocks x 256 thr (4 waves). Wave w owns cols [w*256, w*256+256), all 64 rows.
__launch_bounds__(256, 3)
__global__ void vq_main(const float* __restrict__ lat, const bf16x8* __restrict__ Ep,
                        const float* __restrict__ eNorm, const float* __restrict__ emb,
                        float* __restrict__ out, float* __restrict__ lossAcc) {
    __shared__ char smem[33024];                 // Xs64 (32 KB) / Qs (33 KB) overlay
    unsigned long long* Xs64 = reinterpret_cast<unsigned long long*>(smem); // [q 0..63][r 0..63]
    float* Qs = reinterpret_cast<float*>(smem);  // [r 0..63][129]
    __shared__ float xsqW[4];
    __shared__ unsigned int wbI[256];            // [row][w]
    __shared__ int idxs[64];

    const int t = threadIdx.x;
    const int lane = t & 63;
    const int w = t >> 6;
    const int l15 = lane & 15, lhi = lane >> 4;
    const int R0 = blockIdx.x * 64;
    const float* latB = lat + (R0 >> 10) * (D_DIM * HWSZ) + (R0 & 1023);

    // ---- stage X tile: global (d-major) -> bf16 LDS [q][r], accumulate ||x||^2 ----
    float xsq = 0.0f;
    {
        const int r = lane;
        const int qBase = w * 16;
        #pragma unroll 4
        for (int qi = 0; qi < 16; ++qi) {
            const int q = qBase + qi;
            const float* src = latB + (q * 4) * HWSZ + r;
            float v0 = src[0];
            float v1 = src[HWSZ];
            float v2 = src[2 * HWSZ];
            float v3 = src[3 * HWSZ];
            xsq += v0 * v0 + v1 * v1 + v2 * v2 + v3 * v3;
            Xs64[q * 64 + r] = pack4bf(v0, v1, v2, v3);
        }
    }
    #pragma unroll
    for (int off = 32; off > 0; off >>= 1) xsq += __shfl_down(xsq, off, 64);
    if (lane == 0) xsqW[w] = xsq;
    __syncthreads();

    // ---- MFMA distance + running packed argmin ----
    unsigned int best[4][4];
    #pragma unroll
    for (int i = 0; i < 4; ++i)
        #pragma unroll
        for (int rs = 0; rs < 4; ++rs) best[i][rs] = 0xFFFFFFFFu;

    for (int ct = 0; ct < 4; ++ct) {
        f32x4 acc[4][4];
        #pragma unroll
        for (int j = 0; j < 4; ++j) {
            // fold ||e||^2 into accumulator init: C = -en/2, score = -2*accFinal
            const float c0 = -0.5f * eNorm[w * 256 + ct * 64 + j * 16 + l15];
            #pragma unroll
            for (int i = 0; i < 4; ++i) acc[i][j] = (f32x4){c0, c0, c0, c0};
        }

        #pragma unroll
        for (int dc = 0; dc < 8; ++dc) {
            bf16x8 bfr[4], afr[4];
            #pragma unroll
            for (int j = 0; j < 4; ++j)
                bfr[j] = Ep[((w * 16 + ct * 4 + j) * 8 + dc) * 64 + lane];
            #pragma unroll
            for (int i = 0; i < 4; ++i) {
                const int r = i * 16 + l15;
                union { unsigned long long u[2]; bf16x8 v; } fr;
                fr.u[0] = Xs64[(dc * 8 + lhi) * 64 + r];
                fr.u[1] = Xs64[(dc * 8 + 4 + lhi) * 64 + r];
                afr[i] = fr.v;
            }
            #pragma unroll
            for (int i = 0; i < 4; ++i)
                #pragma unroll
                for (int j = 0; j < 4; ++j)
                    acc[i][j] = __builtin_amdgcn_mfma_f32_16x16x32_bf16(afr[i], bfr[j], acc[i][j], 0, 0, 0);
        }
        #pragma unroll
        for (int j = 0; j < 4; ++j) {
            const unsigned int k = w * 256 + ct * 64 + j * 16 + l15;
            #pragma unroll
            for (int i = 0; i < 4; ++i)
                #pragma unroll
                for (int rs = 0; rs < 4; ++rs) {
                    unsigned int kp = (fkey(-2.0f * acc[i][j][rs]) & 0xFFFFFC00u) | k;
                    best[i][rs] = min(best[i][rs], kp);
                }
        }
    }

    // ---- packed argmin reduce over l15 lanes, dump per-wave candidate ----
    #pragma unroll
    for (int i = 0; i < 4; ++i)
        #pragma unroll
        for (int rs = 0; rs < 4; ++rs) {
            unsigned int v = best[i][rs];
            #pragma unroll
            for (int m = 1; m <= 8; m <<= 1) {
                unsigned int ov = __shfl_xor((int)v, m, 64);
                v = min(v, ov);
            }
            if (l15 == 0) wbI[(i * 16 + lhi * 4 + rs) * 4 + w] = v;
        }
    __syncthreads();

    if (t < 64) {
        unsigned int v0 = min(wbI[t * 4], wbI[t * 4 + 1]);
        unsigned int v1 = min(wbI[t * 4 + 2], wbI[t * 4 + 3]);
        unsigned int bv = min(v0, v1);
        idxs[t] = (int)(bv & 1023u);
        float lsum = fkey_inv(bv);   // ~= eNorm[bi] - 2*dot
        #pragma unroll
        for (int off = 32; off > 0; off >>= 1) lsum += __shfl_down(lsum, off, 64);
        if (t == 0)
            atomicAdd(lossAcc, lsum + xsqW[0] + xsqW[1] + xsqW[2] + xsqW[3]);
    }
    __syncthreads();   // idxs visible; Xs64 dead -> reuse as Qs

    // ---- epilogue: gather emb -> LDS -> full-line coalesced out writes ----
    float* outB = out + (R0 >> 10) * (D_DIM * HWSZ) + (R0 & 1023);
    #pragma unroll
    for (int p = 0; p < 2; ++p) {   // d-halves: full 256B line per d written once
        #pragma unroll
        for (int s = 0; s < 8; ++s) {
            const int slot = s * 256 + t;       // 0..2047
            const int rloc = slot >> 5;         // 0..63
            const int ch = slot & 31;           // float4 chunk in 128 d
            const float4 qv = *reinterpret_cast<const float4*>(
                emb + idxs[rloc] * D_DIM + p * 128 + ch * 4);
            float* dst = &Qs[rloc * 129 + ch * 4];
            dst[0] = qv.x; dst[1] = qv.y; dst[2] = qv.z; dst[3] = qv.w;
        }
        __syncthreads();
        #pragma unroll
        for (int it = 0; it < 32; ++it) {
            const int dp = it * 4 + w;          // 0..127
            outB[(p * 128 + dp) * HWSZ + lane] = Qs[lane * 129 + dp];
        }
        __syncthreads();
    }
}

// -------- finalize: write the two loss scalars --------
__global__ void finalize_kernel(const float* __restrict__ lossAcc,
                                float* __restrict__ out_tail) {
    float mse = *lossAcc * (1.0f / 16777216.0f);
    out_tail[0] = mse;          // embedding_loss
    out_tail[1] = 0.25f * mse;  // BETA * commitment_loss
}

extern "C" void kernel_launch(void* const* d_in, const int* in_sizes, int n_in,
                              void* d_out, int out_size, void* d_ws, size_t ws_size,
                              hipStream_t stream) {
    (void)in_sizes; (void)n_in; (void)out_size; (void)ws_size;
    const float* lat = (const float*)d_in[0];
    const float* emb = (const float*)d_in[1];
    float* out = (float*)d_out;

    char* ws = (char*)d_ws;
    bf16x8* Ep      = (bf16x8*)ws;                       // 512 KB
    float*  eNorm   = (float*)(ws + (512u << 10));       // 4 KB
    float*  lossAcc = eNorm + K_CODES;                   // 4 B

    hipLaunchKernelGGL(pack_e2, dim3(64), dim3(256), 0, stream,
                       emb, (unsigned long long*)Ep, eNorm, lossAcc);
    hipLaunchKernelGGL(vq_main, dim3(1024), dim3(256), 0, stream,
                       lat, Ep, eNorm, emb, out, lossAcc);
    hipLaunchKernelGGL(finalize_kernel, dim3(1), dim3(1), 0, stream,
                       lossAcc, out + OUT_ELEMS);
}

// Round 7
// 240.971 us; speedup vs baseline: 3.5734x; 1.2955x over previous
//
#include <hip/hip_runtime.h>

typedef short bf16x8 __attribute__((ext_vector_type(8)));
typedef float f32x4 __attribute__((ext_vector_type(4)));

#define K_CODES 1024
#define D_DIM   256
#define HWSZ    1024
#define OUT_ELEMS 16777216

__device__ __forceinline__ unsigned short f2bf(float x) {
    unsigned int u = __float_as_uint(x);
    u += 0x7FFFu + ((u >> 16) & 1u);   // RNE
    return (unsigned short)(u >> 16);
}

__device__ __forceinline__ unsigned long long pack4bf(float a, float b, float c, float d) {
    unsigned long long u0 = f2bf(a), u1 = f2bf(b), u2 = f2bf(c), u3 = f2bf(d);
    return u0 | (u1 << 16) | (u2 << 32) | (u3 << 48);
}

// order-preserving float -> uint key (increasing)
__device__ __forceinline__ unsigned int fkey(float s) {
    unsigned int u = __float_as_uint(s);
    return (u & 0x80000000u) ? ~u : (u | 0x80000000u);
}
__device__ __forceinline__ float fkey_inv(unsigned int k) {
    unsigned int u = (k & 0x80000000u) ? (k & 0x7FFFFFFFu) : ~k;
    return __uint_as_float(u);
}

// -------- prep: pack E into B-frag order + ||e||^2 + zero loss --------
// 64 blocks x 256 thr; block = ctile (16 codes x 256 d)
__global__ void pack_e2(const float* __restrict__ emb, unsigned long long* __restrict__ Ep64,
                        float* __restrict__ eNorm, float* __restrict__ lossAcc) {
    const int ctile = blockIdx.x;
    const int t = threadIdx.x;
    const int lane = t & 63;
    #pragma unroll
    for (int p = 0; p < 4; ++p) {
        const int code_loc = p * 4 + (t >> 6);          // 0..15
        const int code = ctile * 16 + code_loc;
        const float4 v = *reinterpret_cast<const float4*>(emb + code * D_DIM + lane * 4);
        float s = v.x * v.x + v.y * v.y + v.z * v.z + v.w * v.w;
        #pragma unroll
        for (int off = 32; off > 0; off >>= 1) s += __shfl_down(s, off, 64);
        if (lane == 0) eNorm[code] = s;
        // frag slot for d0 = lane*4
        const int dc  = lane >> 3;
        const int lhi = lane & 3;
        const int ehi = (lane >> 2) & 1;
        Ep64[(((ctile * 8 + dc) * 64) + lhi * 16 + code_loc) * 2 + ehi] =
            pack4bf(v.x, v.y, v.z, v.w);
    }
    if (ctile == 0 && t == 0) *lossAcc = 0.0f;
}

// -------- fused main: 64-row blocks --------
// 1024 blocks x 256 thr (4 waves). Wave w owns cols [w*256, w*256+256), all 64 rows.
// NOTE: (256,2) — NOT 3/4: min-waves >= 3 forces VGPR<=~85 and the hot loop
// spills (rounds 4/5: 0.5-2.6 GB phantom HBM traffic). At 128 VGPR the HW can
// still reach 4 waves/SIMD naturally.
__launch_bounds__(256, 2)
__global__ void vq_main(const float* __restrict__ lat, const bf16x8* __restrict__ Ep,
                        const float* __restrict__ eNorm, const float* __restrict__ emb,
                        float* __restrict__ out, float* __restrict__ lossAcc) {
    __shared__ char smem[33024];                 // Xs64 (32 KB) / Qs (33 KB) overlay
    unsigned long long* Xs64 = reinterpret_cast<unsigned long long*>(smem); // [q 0..63][r 0..63]
    float* Qs = reinterpret_cast<float*>(smem);  // [r 0..63][129]
    __shared__ float xsqW[4];
    __shared__ unsigned int wbI[256];            // [row][w]
    __shared__ int idxs[64];

    const int t = threadIdx.x;
    const int lane = t & 63;
    const int w = t >> 6;
    const int l15 = lane & 15, lhi = lane >> 4;
    const int R0 = blockIdx.x * 64;
    const float* latB = lat + (R0 >> 10) * (D_DIM * HWSZ) + (R0 & 1023);

    // ---- stage X tile: global (d-major) -> bf16 LDS [q][r], accumulate ||x||^2 ----
    float xsq = 0.0f;
    {
        const int r = lane;
        const int qBase = w * 16;
        #pragma unroll 4
        for (int qi = 0; qi < 16; ++qi) {
            const int q = qBase + qi;
            const float* src = latB + (q * 4) * HWSZ + r;
            float v0 = src[0];
            float v1 = src[HWSZ];
            float v2 = src[2 * HWSZ];
            float v3 = src[3 * HWSZ];
            xsq += v0 * v0 + v1 * v1 + v2 * v2 + v3 * v3;
            Xs64[q * 64 + r] = pack4bf(v0, v1, v2, v3);
        }
    }
    #pragma unroll
    for (int off = 32; off > 0; off >>= 1) xsq += __shfl_down(xsq, off, 64);
    if (lane == 0) xsqW[w] = xsq;
    __syncthreads();

    // ---- MFMA distance + running packed argmin ----
    unsigned int best[4][4];
    #pragma unroll
    for (int i = 0; i < 4; ++i)
        #pragma unroll
        for (int rs = 0; rs < 4; ++rs) best[i][rs] = 0xFFFFFFFFu;

    for (int ct = 0; ct < 4; ++ct) {
        f32x4 acc[4][4];
        #pragma unroll
        for (int j = 0; j < 4; ++j) {
            // fold ||e||^2 into accumulator init: C = -en/2, score = -2*accFinal
            const float c0 = -0.5f * eNorm[w * 256 + ct * 64 + j * 16 + l15];
            #pragma unroll
            for (int i = 0; i < 4; ++i) acc[i][j] = (f32x4){c0, c0, c0, c0};
        }

        #pragma unroll
        for (int dc = 0; dc < 8; ++dc) {
            bf16x8 bfr[4], afr[4];
            #pragma unroll
            for (int j = 0; j < 4; ++j)
                bfr[j] = Ep[((w * 16 + ct * 4 + j) * 8 + dc) * 64 + lane];
            #pragma unroll
            for (int i = 0; i < 4; ++i) {
                const int r = i * 16 + l15;
                union { unsigned long long u[2]; bf16x8 v; } fr;
                fr.u[0] = Xs64[(dc * 8 + lhi) * 64 + r];
                fr.u[1] = Xs64[(dc * 8 + 4 + lhi) * 64 + r];
                afr[i] = fr.v;
            }
            #pragma unroll
            for (int i = 0; i < 4; ++i)
                #pragma unroll
                for (int j = 0; j < 4; ++j)
                    acc[i][j] = __builtin_amdgcn_mfma_f32_16x16x32_bf16(afr[i], bfr[j], acc[i][j], 0, 0, 0);
        }
        #pragma unroll
        for (int j = 0; j < 4; ++j) {
            const unsigned int k = w * 256 + ct * 64 + j * 16 + l15;
            #pragma unroll
            for (int i = 0; i < 4; ++i)
                #pragma unroll
                for (int rs = 0; rs < 4; ++rs) {
                    unsigned int kp = (fkey(-2.0f * acc[i][j][rs]) & 0xFFFFFC00u) | k;
                    best[i][rs] = min(best[i][rs], kp);
                }
        }
    }

    // ---- packed argmin reduce over l15 lanes, dump per-wave candidate ----
    #pragma unroll
    for (int i = 0; i < 4; ++i)
        #pragma unroll
        for (int rs = 0; rs < 4; ++rs) {
            unsigned int v = best[i][rs];
            #pragma unroll
            for (int m = 1; m <= 8; m <<= 1) {
                unsigned int ov = __shfl_xor((int)v, m, 64);
                v = min(v, ov);
            }
            if (l15 == 0) wbI[(i * 16 + lhi * 4 + rs) * 4 + w] = v;
        }
    __syncthreads();

    if (t < 64) {
        unsigned int v0 = min(wbI[t * 4], wbI[t * 4 + 1]);
        unsigned int v1 = min(wbI[t * 4 + 2], wbI[t * 4 + 3]);
        unsigned int bv = min(v0, v1);
        idxs[t] = (int)(bv & 1023u);
        float lsum = fkey_inv(bv);   // ~= eNorm[bi] - 2*dot
        #pragma unroll
        for (int off = 32; off > 0; off >>= 1) lsum += __shfl_down(lsum, off, 64);
        if (t == 0)
            atomicAdd(lossAcc, lsum + xsqW[0] + xsqW[1] + xsqW[2] + xsqW[3]);
    }
    __syncthreads();   // idxs visible; Xs64 dead -> reuse as Qs

    // ---- epilogue: gather emb -> LDS -> full-line coalesced out writes ----
    float* outB = out + (R0 >> 10) * (D_DIM * HWSZ) + (R0 & 1023);
    #pragma unroll
    for (int p = 0; p < 2; ++p) {   // d-halves: full 256B line per d written once
        #pragma unroll
        for (int s = 0; s < 8; ++s) {
            const int slot = s * 256 + t;       // 0..2047
            const int rloc = slot >> 5;         // 0..63
            const int ch = slot & 31;           // float4 chunk in 128 d
            const float4 qv = *reinterpret_cast<const float4*>(
                emb + idxs[rloc] * D_DIM + p * 128 + ch * 4);
            float* dst = &Qs[rloc * 129 + ch * 4];
            dst[0] = qv.x; dst[1] = qv.y; dst[2] = qv.z; dst[3] = qv.w;
        }
        __syncthreads();
        #pragma unroll
        for (int it = 0; it < 32; ++it) {
            const int dp = it * 4 + w;          // 0..127
            outB[(p * 128 + dp) * HWSZ + lane] = Qs[lane * 129 + dp];
        }
        __syncthreads();
    }
}

// -------- finalize: write the two loss scalars --------
__global__ void finalize_kernel(const float* __restrict__ lossAcc,
                                float* __restrict__ out_tail) {
    float mse = *lossAcc * (1.0f / 16777216.0f);
    out_tail[0] = mse;          // embedding_loss
    out_tail[1] = 0.25f * mse;  // BETA * commitment_loss
}

extern "C" void kernel_launch(void* const* d_in, const int* in_sizes, int n_in,
                              void* d_out, int out_size, void* d_ws, size_t ws_size,
                              hipStream_t stream) {
    (void)in_sizes; (void)n_in; (void)out_size; (void)ws_size;
    const float* lat = (const float*)d_in[0];
    const float* emb = (const float*)d_in[1];
    float* out = (float*)d_out;

    char* ws = (char*)d_ws;
    bf16x8* Ep      = (bf16x8*)ws;                       // 512 KB
    float*  eNorm   = (float*)(ws + (512u << 10));       // 4 KB
    float*  lossAcc = eNorm + K_CODES;                   // 4 B

    hipLaunchKernelGGL(pack_e2, dim3(64), dim3(256), 0, stream,
                       emb, (unsigned long long*)Ep, eNorm, lossAcc);
    hipLaunchKernelGGL(vq_main, dim3(1024), dim3(256), 0, stream,
                       lat, Ep, eNorm, emb, out, lossAcc);
    hipLaunchKernelGGL(finalize_kernel, dim3(1), dim3(1), 0, stream,
                       lossAcc, out + OUT_ELEMS);
}